// Round 8
// baseline (122.475 us; speedup 1.0000x reference)
//
#include <hip/hip_runtime.h>
#include <hip/hip_bf16.h>

typedef __attribute__((ext_vector_type(8))) short short8;
typedef __attribute__((ext_vector_type(16))) float f32x16;
typedef __attribute__((ext_vector_type(2))) unsigned uint2v;

#define LEAK 0.01f

__device__ __forceinline__ f32x16 mfma32(short8 a, short8 b, f32x16 c) {
    return __builtin_amdgcn_mfma_f32_32x32x16_bf16(a, b, c, 0, 0, 0);
}
__device__ __forceinline__ unsigned pkbf(float a, float b) {
    __hip_bfloat162 t = __float22bfloat162_rn(make_float2(a, b));
    return *reinterpret_cast<unsigned*>(&t);
}

// Half-wave swap. Target semantics (proven correct in round 5):
//   a' = [a_lo, b_lo], b' = [a_hi, b_hi]  (lo = lanes<32 half, hi = lanes>=32 half)
#if defined(__has_builtin) && __has_builtin(__builtin_amdgcn_permlane32_swap)
__device__ __forceinline__ void plswap(unsigned &a, unsigned &b, int /*h*/) {
    uint2v r = __builtin_amdgcn_permlane32_swap(a, b, false, false);
    a = r.x; b = r.y;
}
#else
__device__ __forceinline__ void plswap(unsigned &a, unsigned &b, int h) {
    unsigned ax = (unsigned)__shfl_xor((int)a, 32);
    unsigned bx = (unsigned)__shfl_xor((int)b, 32);
    unsigned na = h ? bx : a;
    unsigned nb = h ? b  : ax;
    a = na; b = nb;
}
#endif

// Layer transition, fully in-register: acc (2x f32x16, D-layout rows
// (q&3)+8*(q>>2)+4h + 32nt, col=batch) -> 4 B-frags (k=16ks+8h+{0..7}),
// with leaky ReLU. pk[nt][s] = rows n0,n0+1, n0 = 32nt+8*(s>>1)+2*(s&1)+4h.
// dword d of out[ks] needs rows 16ks+8h+2d,+1  ->  s=4(ks&1)+2h+(d&1), h'=d>>1.
__device__ __forceinline__ void transition(const f32x16 &A0, const f32x16 &A1,
                                           short8 out[4], int h) {
    unsigned pk[2][8];
    #pragma unroll
    for (int nt = 0; nt < 2; ++nt) {
        const f32x16 &A = nt ? A1 : A0;
        #pragma unroll
        for (int s = 0; s < 8; ++s) {
            float u = A[2*s], v = A[2*s+1];
            u = fmaxf(u, LEAK * u); v = fmaxf(v, LEAK * v);
            pk[nt][s] = pkbf(u, v);
        }
    }
    #pragma unroll
    for (int ks = 0; ks < 4; ++ks) {
        const int nt = ks >> 1, ss = (ks & 1) * 4;
        unsigned d0 = pk[nt][ss], d1 = pk[nt][ss+1], d2 = pk[nt][ss+2], d3 = pk[nt][ss+3];
        plswap(d0, d2, h);   // d0 = dword0, d2 = dword2
        plswap(d1, d3, h);   // d1 = dword1, d3 = dword3
        union { unsigned u[4]; short8 s; } U;
        U.u[0] = d0; U.u[1] = d1; U.u[2] = d2; U.u[3] = d3;
        out[ks] = U.s;
    }
}

// ---------------- prep: bf16 + diag-mask + bias K-padding ----------------
// xp [8192][144]: k<128 = x, k==128 = 1, else 0
// w0p[128][64][144]: k<128 = w0 (j==t zeroed), k==128 = b0, else 0
// w1p[128][64][80]:  k<64 = w1, k==64 = b1, else 0
// w2p[128][32][80]:  n<2: k<64 = w2, k==64 = b2; else 0
__global__ __launch_bounds__(256) void prep_kernel(
    const float* __restrict__ x,  const float* __restrict__ w0, const float* __restrict__ b0,
    const float* __restrict__ w1, const float* __restrict__ b1,
    const float* __restrict__ w2, const float* __restrict__ b2,
    __hip_bfloat16* __restrict__ xp,  __hip_bfloat16* __restrict__ w0p,
    __hip_bfloat16* __restrict__ w1p, __hip_bfloat16* __restrict__ w2p)
{
    const int idx = blockIdx.x * 256 + threadIdx.x;
    float v[8];
    #pragma unroll
    for (int e = 0; e < 8; ++e) v[e] = 0.f;
    __hip_bfloat16* dst;

    if (idx < 147456) {                       // xp
        int b = idx / 18, ch = idx - b * 18;
        dst = xp + b * 144 + ch * 8;
        if (ch < 16) {
            const float* s = x + b * 128 + ch * 8;
            #pragma unroll
            for (int e = 0; e < 8; ++e) v[e] = s[e];
        } else if (ch == 16) v[0] = 1.f;
    } else if (idx < 294912) {                // w0p
        int i = idx - 147456;
        int r = i / 18, ch = i - r * 18;      // r = t*64+n
        int t = r >> 6;
        dst = w0p + r * 144 + ch * 8;
        if (ch < 16) {
            const float* s = w0 + r * 128 + ch * 8;
            #pragma unroll
            for (int e = 0; e < 8; ++e) v[e] = s[e];
            if ((t >> 3) == ch) v[t & 7] = 0.f;   // mask j == t
        } else if (ch == 16) v[0] = b0[r];
    } else if (idx < 376832) {                // w1p
        int i = idx - 294912;
        int r = i / 10, ch = i - r * 10;
        dst = w1p + r * 80 + ch * 8;
        if (ch < 8) {
            const float* s = w1 + r * 64 + ch * 8;
            #pragma unroll
            for (int e = 0; e < 8; ++e) v[e] = s[e];
        } else if (ch == 8) v[0] = b1[r];
    } else {                                  // w2p
        int i = idx - 376832;
        int r = i / 10, ch = i - r * 10;      // r = t*32+n
        int t = r >> 5, n = r & 31;
        dst = w2p + r * 80 + ch * 8;
        if (n < 2) {
            if (ch < 8) {
                const float* s = w2 + (t * 2 + n) * 64 + ch * 8;
                #pragma unroll
                for (int e = 0; e < 8; ++e) v[e] = s[e];
            } else if (ch == 8) v[0] = b2[t * 2 + n];
        }
    }
    union { unsigned u[4]; short8 s; } U;
    #pragma unroll
    for (int p = 0; p < 4; ++p) U.u[p] = pkbf(v[2*p], v[2*p+1]);
    *reinterpret_cast<short8*>(dst) = U.s;
}

// ---------------- main fused MLP: 32x32 MFMA, permlane transitions, ----------------
// ---------------- software-pipelined (L0 of tile t+1 overlaps trans1 of t) --------
// grid 1024 x 256. block -> (t, 1024 rows); wave -> 256 rows = 8 tiles of 32.
__global__ __launch_bounds__(256, 2) void mlp_kernel(
    const __hip_bfloat16* __restrict__ xp,
    const __hip_bfloat16* __restrict__ w0p,
    const __hip_bfloat16* __restrict__ w1p,
    const __hip_bfloat16* __restrict__ w2p,
    float* __restrict__ dst, int direct)
{
    const int tid  = threadIdx.x;
    const int wave = tid >> 6;
    const int lane = tid & 63;
    const int h    = lane >> 5;
    const int c    = lane & 31;

    const int bid   = blockIdx.x;
    const int t     = (bid & 7) * 16 + ((bid >> 3) & 15);  // XCD k owns t in [16k,16k+16)
    const int chunk = bid >> 7;                            // 0..7
    const int rb0   = chunk * 1024 + wave * 256;

    // ---- x B-frags for tile 0 (on the critical path: issue first) ----
    const __hip_bfloat16* xr0 = xp + (rb0 + c) * 144 + h * 8;
    short8 xf[9];
    #pragma unroll
    for (int ks = 0; ks < 9; ++ks)
        xf[ks] = *reinterpret_cast<const short8*>(xr0 + ks * 16);

    // ---- weight A-fragments, register-resident (A[n][k]: n=32nt+c, k=16ks+8h+e) ----
    const __hip_bfloat16* w0t = w0p + t * 9216;
    const __hip_bfloat16* w1t = w1p + t * 5120;
    const __hip_bfloat16* w2t = w2p + t * 2560;
    short8 w0f[2][9], w1f[2][5], w2f[5];
    #pragma unroll
    for (int nt = 0; nt < 2; ++nt)
        #pragma unroll
        for (int ks = 0; ks < 9; ++ks)
            w0f[nt][ks] = *reinterpret_cast<const short8*>(w0t + (nt*32 + c)*144 + ks*16 + h*8);
    #pragma unroll
    for (int nt = 0; nt < 2; ++nt)
        #pragma unroll
        for (int ks = 0; ks < 5; ++ks)
            w1f[nt][ks] = *reinterpret_cast<const short8*>(w1t + (nt*32 + c)*80 + ks*16 + h*8);
    #pragma unroll
    for (int ks = 0; ks < 5; ++ks)
        w2f[ks] = *reinterpret_cast<const short8*>(w2t + c*80 + ks*16 + h*8);

    // constant B-frag for the bias row (k=64 -> 1.0): h==0, e==0 slot
    union { unsigned u[4]; short8 s; } OneU;
    OneU.u[0] = (h == 0) ? 0x00003f80u : 0u;
    OneU.u[1] = 0u; OneU.u[2] = 0u; OneU.u[3] = 0u;
    const short8 onef = OneU.s;

    // ---- prologue: L0 of tile 0 into parity 0 ----
    f32x16 acc0a[2], acc0b[2];
    #pragma unroll
    for (int i = 0; i < 16; ++i) { acc0a[0][i] = 0.f; acc0b[0][i] = 0.f; }
    __builtin_amdgcn_s_setprio(1);
    #pragma unroll
    for (int ks = 0; ks < 9; ++ks) {
        acc0a[0] = mfma32(w0f[0][ks], xf[ks], acc0a[0]);
        acc0b[0] = mfma32(w0f[1][ks], xf[ks], acc0b[0]);
    }
    __builtin_amdgcn_s_setprio(0);

    #pragma unroll
    for (int tile = 0; tile < 8; ++tile) {
        const int cur = tile & 1, nxt = cur ^ 1;   // compile-time after unroll
        const int brow = rb0 + tile * 32 + c;

        // ---- issue next tile's x loads (xf regs dead: consumed by previous L0) ----
        if (tile < 7) {
            const __hip_bfloat16* xr = xr0 + (tile + 1) * (32 * 144);
            #pragma unroll
            for (int ks = 0; ks < 9; ++ks)
                xf[ks] = *reinterpret_cast<const short8*>(xr + ks * 16);
        }

        // ---- trans0(t): VALU (overlaps prior MFMA drain) ----
        short8 h1f[4];
        transition(acc0a[cur], acc0b[cur], h1f, h);

        // ---- layer 1: 10 MFMA ----
        f32x16 acc1a, acc1b;
        #pragma unroll
        for (int i = 0; i < 16; ++i) { acc1a[i] = 0.f; acc1b[i] = 0.f; }
        __builtin_amdgcn_s_setprio(1);
        #pragma unroll
        for (int ks = 0; ks < 4; ++ks) {
            acc1a = mfma32(w1f[0][ks], h1f[ks], acc1a);
            acc1b = mfma32(w1f[1][ks], h1f[ks], acc1b);
        }
        acc1a = mfma32(w1f[0][4], onef, acc1a);
        acc1b = mfma32(w1f[1][4], onef, acc1b);
        __builtin_amdgcn_s_setprio(0);

        // ---- L0 of tile t+1 (18 MFMA): fills the pipe under trans1 below ----
        if (tile < 7) {
            #pragma unroll
            for (int i = 0; i < 16; ++i) { acc0a[nxt][i] = 0.f; acc0b[nxt][i] = 0.f; }
            __builtin_amdgcn_s_setprio(1);
            #pragma unroll
            for (int ks = 0; ks < 9; ++ks) {
                acc0a[nxt] = mfma32(w0f[0][ks], xf[ks], acc0a[nxt]);
                acc0b[nxt] = mfma32(w0f[1][ks], xf[ks], acc0b[nxt]);
            }
            __builtin_amdgcn_s_setprio(0);
        }

        // ---- trans1(t): VALU, overlaps the L0 MFMA drain ----
        short8 h2f[4];
        transition(acc1a, acc1b, h2f, h);

        // ---- layer 2: 5 MFMA (rows 0,1 real) ----
        f32x16 acc2;
        #pragma unroll
        for (int i = 0; i < 16; ++i) acc2[i] = 0.f;
        __builtin_amdgcn_s_setprio(1);
        #pragma unroll
        for (int ks = 0; ks < 4; ++ks) acc2 = mfma32(w2f[ks], h2f[ks], acc2);
        acc2 = mfma32(w2f[4], onef, acc2);
        __builtin_amdgcn_s_setprio(0);

        // ---- store: lanes h==0 hold out[p=0][b]=reg0, out[p=1][b]=reg1 ----
        if (h == 0) {
            float2 v = make_float2(acc2[0], acc2[1]);
            if (direct) *reinterpret_cast<float2*>(dst + brow * 256 + t * 2) = v;
            else        *reinterpret_cast<float2*>(dst + t * 16384 + brow * 2) = v;
        }
    }
}

// ---------------- transpose: tmp[128][8192][2] f32 -> out[8192][256] ----------------
__global__ __launch_bounds__(256) void transpose_kernel(
    const float* __restrict__ tmp, float* __restrict__ out)
{
    __shared__ float tile[32][257];
    const int b0 = blockIdx.x * 32;
    const int tid = threadIdx.x;
    #pragma unroll
    for (int it = 0; it < 16; ++it) {
        int idx = it * 256 + tid;
        int tt = idx >> 5, r = idx & 31;
        float2 v = *reinterpret_cast<const float2*>(tmp + tt * 16384 + (b0 + r) * 2);
        tile[r][tt * 2]     = v.x;
        tile[r][tt * 2 + 1] = v.y;
    }
    __syncthreads();
    #pragma unroll
    for (int r = 0; r < 32; ++r)
        out[(b0 + r) * 256 + tid] = tile[r][tid];
}

extern "C" void kernel_launch(void* const* d_in, const int* in_sizes, int n_in,
                              void* d_out, int out_size, void* d_ws, size_t ws_size,
                              hipStream_t stream)
{
    const float* x  = (const float*)d_in[0];
    const float* w0 = (const float*)d_in[1];
    const float* b0 = (const float*)d_in[2];
    const float* w1 = (const float*)d_in[3];
    const float* b1 = (const float*)d_in[4];
    const float* w2 = (const float*)d_in[5];
    const float* b2 = (const float*)d_in[6];
    float* out = (float*)d_out;

    const size_t OFF_W0  = 2359296;            // xp : 8192*144*2
    const size_t OFF_W1  = OFF_W0 + 2359296;   // w0p: 128*64*144*2
    const size_t OFF_W2  = OFF_W1 + 1310720;   // w1p: 128*64*80*2
    const size_t OFF_TMP = OFF_W2 + 655360;    // w2p: 128*32*80*2  -> 6684672
    const size_t NEED_TMP = OFF_TMP + 8388608; // + tmp 128*8192*2*4

    if (ws_size < OFF_TMP) return;

    char* ws = (char*)d_ws;
    __hip_bfloat16* xp  = (__hip_bfloat16*)(ws);
    __hip_bfloat16* w0p = (__hip_bfloat16*)(ws + OFF_W0);
    __hip_bfloat16* w1p = (__hip_bfloat16*)(ws + OFF_W1);
    __hip_bfloat16* w2p = (__hip_bfloat16*)(ws + OFF_W2);
    float* tmp = (float*)(ws + OFF_TMP);

    const int use_tmp = (ws_size >= NEED_TMP) ? 1 : 0;
    float* dstp = use_tmp ? tmp : out;

    prep_kernel<<<1632, 256, 0, stream>>>(x, w0, b0, w1, b1, w2, b2, xp, w0p, w1p, w2p);
    mlp_kernel<<<1024, 256, 0, stream>>>(xp, w0p, w1p, w2p, dstp, use_tmp ? 0 : 1);
    if (use_tmp)
        transpose_kernel<<<256, 256, 0, stream>>>(tmp, out);
}

// Round 9
// 119.374 us; speedup vs baseline: 1.0260x; 1.0260x over previous
//
#include <hip/hip_runtime.h>
#include <hip/hip_bf16.h>

typedef __attribute__((ext_vector_type(8))) short short8;
typedef __attribute__((ext_vector_type(16))) float f32x16;
typedef __attribute__((ext_vector_type(2))) unsigned uint2v;

#define LEAK 0.01f

__device__ __forceinline__ f32x16 mfma32(short8 a, short8 b, f32x16 c) {
    return __builtin_amdgcn_mfma_f32_32x32x16_bf16(a, b, c, 0, 0, 0);
}
__device__ __forceinline__ unsigned pkbf(float a, float b) {
    __hip_bfloat162 t = __float22bfloat162_rn(make_float2(a, b));
    return *reinterpret_cast<unsigned*>(&t);
}

// Half-wave swap. Target semantics (proven correct in round 5):
//   a' = [a_lo, b_lo], b' = [a_hi, b_hi]  (lo = lanes<32 half, hi = lanes>=32 half)
#if defined(__has_builtin) && __has_builtin(__builtin_amdgcn_permlane32_swap)
__device__ __forceinline__ void plswap(unsigned &a, unsigned &b, int /*h*/) {
    uint2v r = __builtin_amdgcn_permlane32_swap(a, b, false, false);
    a = r.x; b = r.y;
}
#else
__device__ __forceinline__ void plswap(unsigned &a, unsigned &b, int h) {
    unsigned ax = (unsigned)__shfl_xor((int)a, 32);
    unsigned bx = (unsigned)__shfl_xor((int)b, 32);
    unsigned na = h ? bx : a;
    unsigned nb = h ? b  : ax;
    a = na; b = nb;
}
#endif

// Layer transition, fully in-register: acc (2x f32x16, D-layout rows
// (q&3)+8*(q>>2)+4h + 32nt, col=batch) -> 4 B-frags (k=16ks+8h+{0..7}),
// with leaky ReLU. pk[nt][s] = rows n0,n0+1, n0 = 32nt+8*(s>>1)+2*(s&1)+4h.
// dword d of out[ks] needs rows 16ks+8h+2d,+1  ->  s=4(ks&1)+2h+(d&1), h'=d>>1.
__device__ __forceinline__ void transition(const f32x16 &A0, const f32x16 &A1,
                                           short8 out[4], int h) {
    unsigned pk[2][8];
    #pragma unroll
    for (int nt = 0; nt < 2; ++nt) {
        const f32x16 &A = nt ? A1 : A0;
        #pragma unroll
        for (int s = 0; s < 8; ++s) {
            float u = A[2*s], v = A[2*s+1];
            u = fmaxf(u, LEAK * u); v = fmaxf(v, LEAK * v);
            pk[nt][s] = pkbf(u, v);
        }
    }
    #pragma unroll
    for (int ks = 0; ks < 4; ++ks) {
        const int nt = ks >> 1, ss = (ks & 1) * 4;
        unsigned d0 = pk[nt][ss], d1 = pk[nt][ss+1], d2 = pk[nt][ss+2], d3 = pk[nt][ss+3];
        plswap(d0, d2, h);   // d0 = dword0, d2 = dword2
        plswap(d1, d3, h);   // d1 = dword1, d3 = dword3
        union { unsigned u[4]; short8 s; } U;
        U.u[0] = d0; U.u[1] = d1; U.u[2] = d2; U.u[3] = d3;
        out[ks] = U.s;
    }
}

// ---------------- prep: bf16 + diag-mask + bias K-padding ----------------
// xp [8192][144]: k<128 = x, k==128 = 1, else 0
// w0p[128][64][144]: k<128 = w0 (j==t zeroed), k==128 = b0, else 0
// w1p[128][64][80]:  k<64 = w1, k==64 = b1, else 0
// w2p[128][32][80]:  n<2: k<64 = w2, k==64 = b2; else 0
__global__ __launch_bounds__(256) void prep_kernel(
    const float* __restrict__ x,  const float* __restrict__ w0, const float* __restrict__ b0,
    const float* __restrict__ w1, const float* __restrict__ b1,
    const float* __restrict__ w2, const float* __restrict__ b2,
    __hip_bfloat16* __restrict__ xp,  __hip_bfloat16* __restrict__ w0p,
    __hip_bfloat16* __restrict__ w1p, __hip_bfloat16* __restrict__ w2p)
{
    const int idx = blockIdx.x * 256 + threadIdx.x;
    float v[8];
    #pragma unroll
    for (int e = 0; e < 8; ++e) v[e] = 0.f;
    __hip_bfloat16* dst;

    if (idx < 147456) {                       // xp
        int b = idx / 18, ch = idx - b * 18;
        dst = xp + b * 144 + ch * 8;
        if (ch < 16) {
            const float* s = x + b * 128 + ch * 8;
            #pragma unroll
            for (int e = 0; e < 8; ++e) v[e] = s[e];
        } else if (ch == 16) v[0] = 1.f;
    } else if (idx < 294912) {                // w0p
        int i = idx - 147456;
        int r = i / 18, ch = i - r * 18;      // r = t*64+n
        int t = r >> 6;
        dst = w0p + r * 144 + ch * 8;
        if (ch < 16) {
            const float* s = w0 + r * 128 + ch * 8;
            #pragma unroll
            for (int e = 0; e < 8; ++e) v[e] = s[e];
            if ((t >> 3) == ch) v[t & 7] = 0.f;   // mask j == t
        } else if (ch == 16) v[0] = b0[r];
    } else if (idx < 376832) {                // w1p
        int i = idx - 294912;
        int r = i / 10, ch = i - r * 10;
        dst = w1p + r * 80 + ch * 8;
        if (ch < 8) {
            const float* s = w1 + r * 64 + ch * 8;
            #pragma unroll
            for (int e = 0; e < 8; ++e) v[e] = s[e];
        } else if (ch == 8) v[0] = b1[r];
    } else {                                  // w2p
        int i = idx - 376832;
        int r = i / 10, ch = i - r * 10;      // r = t*32+n
        int t = r >> 5, n = r & 31;
        dst = w2p + r * 80 + ch * 8;
        if (n < 2) {
            if (ch < 8) {
                const float* s = w2 + (t * 2 + n) * 64 + ch * 8;
                #pragma unroll
                for (int e = 0; e < 8; ++e) v[e] = s[e];
            } else if (ch == 8) v[0] = b2[t * 2 + n];
        }
    }
    union { unsigned u[4]; short8 s; } U;
    #pragma unroll
    for (int p = 0; p < 4; ++p) U.u[p] = pkbf(v[2*p], v[2*p+1]);
    *reinterpret_cast<short8*>(dst) = U.s;
}

// ---------------- main fused MLP: 32x32 MFMA + permlane transitions ----------------
// grid 1024 x 256. block -> (t, 1024 rows); wave -> 256 rows = 8 tiles of 32.
// R9: first MFMA of every chain reads a persistent zero C-vector (no per-tile
// accumulator zero-init), full unroll. Phase order identical to R7.
__global__ __launch_bounds__(256, 2) void mlp_kernel(
    const __hip_bfloat16* __restrict__ xp,
    const __hip_bfloat16* __restrict__ w0p,
    const __hip_bfloat16* __restrict__ w1p,
    const __hip_bfloat16* __restrict__ w2p,
    float* __restrict__ dst, int direct)
{
    const int tid  = threadIdx.x;
    const int wave = tid >> 6;
    const int lane = tid & 63;
    const int h    = lane >> 5;
    const int c    = lane & 31;

    const int bid   = blockIdx.x;
    const int t     = (bid & 7) * 16 + ((bid >> 3) & 15);  // XCD k owns t in [16k,16k+16)
    const int chunk = bid >> 7;                            // 0..7
    const int rb0   = chunk * 1024 + wave * 256;

    // ---- x B-frags for tile 0 (on the critical path: issue first) ----
    const __hip_bfloat16* xr0 = xp + (rb0 + c) * 144 + h * 8;
    short8 xf[9];
    #pragma unroll
    for (int ks = 0; ks < 9; ++ks)
        xf[ks] = *reinterpret_cast<const short8*>(xr0 + ks * 16);

    // ---- weight A-fragments, register-resident (A[n][k]: n=32nt+c, k=16ks+8h+e) ----
    const __hip_bfloat16* w0t = w0p + t * 9216;
    const __hip_bfloat16* w1t = w1p + t * 5120;
    const __hip_bfloat16* w2t = w2p + t * 2560;
    short8 w0f[2][9], w1f[2][5], w2f[5];
    #pragma unroll
    for (int nt = 0; nt < 2; ++nt)
        #pragma unroll
        for (int ks = 0; ks < 9; ++ks)
            w0f[nt][ks] = *reinterpret_cast<const short8*>(w0t + (nt*32 + c)*144 + ks*16 + h*8);
    #pragma unroll
    for (int nt = 0; nt < 2; ++nt)
        #pragma unroll
        for (int ks = 0; ks < 5; ++ks)
            w1f[nt][ks] = *reinterpret_cast<const short8*>(w1t + (nt*32 + c)*80 + ks*16 + h*8);
    #pragma unroll
    for (int ks = 0; ks < 5; ++ks)
        w2f[ks] = *reinterpret_cast<const short8*>(w2t + c*80 + ks*16 + h*8);

    // constant B-frag for the bias row (k=64 -> 1.0): h==0, e==0 slot
    union { unsigned u[4]; short8 s; } OneU;
    OneU.u[0] = (h == 0) ? 0x00003f80u : 0u;
    OneU.u[1] = 0u; OneU.u[2] = 0u; OneU.u[3] = 0u;
    const short8 onef = OneU.s;

    // persistent zero C-vector: first MFMA of each chain reads this (D != C),
    // eliminating the 80 v_accvgpr_write zero-inits per tile.
    f32x16 ZV;
    #pragma unroll
    for (int i = 0; i < 16; ++i) ZV[i] = 0.f;

    #pragma unroll
    for (int tile = 0; tile < 8; ++tile) {
        const int brow = rb0 + tile * 32 + c;

        // ---- prefetch next tile's x B-frags (latency hides under 3 layers) ----
        short8 xn[9];
        if (tile < 7) {
            const __hip_bfloat16* xr = xr0 + (tile + 1) * (32 * 144);
            #pragma unroll
            for (int ks = 0; ks < 9; ++ks)
                xn[ks] = *reinterpret_cast<const short8*>(xr + ks * 16);
        }

        // ---- layer 0: 18 MFMA (bias via K-pad col 128), C-init from ZV ----
        f32x16 acc0a, acc0b;
        __builtin_amdgcn_s_setprio(1);
        acc0a = mfma32(w0f[0][0], xf[0], ZV);
        acc0b = mfma32(w0f[1][0], xf[0], ZV);
        #pragma unroll
        for (int ks = 1; ks < 9; ++ks) {
            acc0a = mfma32(w0f[0][ks], xf[ks], acc0a);
            acc0b = mfma32(w0f[1][ks], xf[ks], acc0b);
        }
        __builtin_amdgcn_s_setprio(0);

        short8 h1f[4];
        transition(acc0a, acc0b, h1f, h);

        // ---- layer 1: 10 MFMA (bias row via onef), C-init from ZV ----
        f32x16 acc1a, acc1b;
        __builtin_amdgcn_s_setprio(1);
        acc1a = mfma32(w1f[0][0], h1f[0], ZV);
        acc1b = mfma32(w1f[1][0], h1f[0], ZV);
        #pragma unroll
        for (int ks = 1; ks < 4; ++ks) {
            acc1a = mfma32(w1f[0][ks], h1f[ks], acc1a);
            acc1b = mfma32(w1f[1][ks], h1f[ks], acc1b);
        }
        acc1a = mfma32(w1f[0][4], onef, acc1a);
        acc1b = mfma32(w1f[1][4], onef, acc1b);
        __builtin_amdgcn_s_setprio(0);

        short8 h2f[4];
        transition(acc1a, acc1b, h2f, h);

        // ---- layer 2: 5 MFMA (rows 0,1 real), C-init from ZV ----
        f32x16 acc2;
        __builtin_amdgcn_s_setprio(1);
        acc2 = mfma32(w2f[0], h2f[0], ZV);
        #pragma unroll
        for (int ks = 1; ks < 4; ++ks) acc2 = mfma32(w2f[ks], h2f[ks], acc2);
        acc2 = mfma32(w2f[4], onef, acc2);
        __builtin_amdgcn_s_setprio(0);

        // ---- store: lanes h==0 hold out[p=0][b]=reg0, out[p=1][b]=reg1 ----
        if (h == 0) {
            float2 v = make_float2(acc2[0], acc2[1]);
            if (direct) *reinterpret_cast<float2*>(dst + brow * 256 + t * 2) = v;
            else        *reinterpret_cast<float2*>(dst + t * 16384 + brow * 2) = v;
        }

        #pragma unroll
        for (int ks = 0; ks < 9; ++ks) xf[ks] = xn[ks];
    }
}

// ---------------- transpose: tmp[128][8192][2] f32 -> out[8192][256] ----------------
__global__ __launch_bounds__(256) void transpose_kernel(
    const float* __restrict__ tmp, float* __restrict__ out)
{
    __shared__ float tile[32][257];
    const int b0 = blockIdx.x * 32;
    const int tid = threadIdx.x;
    #pragma unroll
    for (int it = 0; it < 16; ++it) {
        int idx = it * 256 + tid;
        int tt = idx >> 5, r = idx & 31;
        float2 v = *reinterpret_cast<const float2*>(tmp + tt * 16384 + (b0 + r) * 2);
        tile[r][tt * 2]     = v.x;
        tile[r][tt * 2 + 1] = v.y;
    }
    __syncthreads();
    #pragma unroll
    for (int r = 0; r < 32; ++r)
        out[(b0 + r) * 256 + tid] = tile[r][tid];
}

extern "C" void kernel_launch(void* const* d_in, const int* in_sizes, int n_in,
                              void* d_out, int out_size, void* d_ws, size_t ws_size,
                              hipStream_t stream)
{
    const float* x  = (const float*)d_in[0];
    const float* w0 = (const float*)d_in[1];
    const float* b0 = (const float*)d_in[2];
    const float* w1 = (const float*)d_in[3];
    const float* b1 = (const float*)d_in[4];
    const float* w2 = (const float*)d_in[5];
    const float* b2 = (const float*)d_in[6];
    float* out = (float*)d_out;

    const size_t OFF_W0  = 2359296;            // xp : 8192*144*2
    const size_t OFF_W1  = OFF_W0 + 2359296;   // w0p: 128*64*144*2
    const size_t OFF_W2  = OFF_W1 + 1310720;   // w1p: 128*64*80*2
    const size_t OFF_TMP = OFF_W2 + 655360;    // w2p: 128*32*80*2  -> 6684672
    const size_t NEED_TMP = OFF_TMP + 8388608; // + tmp 128*8192*2*4

    if (ws_size < OFF_TMP) return;

    char* ws = (char*)d_ws;
    __hip_bfloat16* xp  = (__hip_bfloat16*)(ws);
    __hip_bfloat16* w0p = (__hip_bfloat16*)(ws + OFF_W0);
    __hip_bfloat16* w1p = (__hip_bfloat16*)(ws + OFF_W1);
    __hip_bfloat16* w2p = (__hip_bfloat16*)(ws + OFF_W2);
    float* tmp = (float*)(ws + OFF_TMP);

    const int use_tmp = (ws_size >= NEED_TMP) ? 1 : 0;
    float* dstp = use_tmp ? tmp : out;

    prep_kernel<<<1632, 256, 0, stream>>>(x, w0, b0, w1, b1, w2, b2, xp, w0p, w1p, w2p);
    mlp_kernel<<<1024, 256, 0, stream>>>(xp, w0p, w1p, w2p, dstp, use_tmp ? 0 : 1);
    if (use_tmp)
        transpose_kernel<<<256, 256, 0, stream>>>(tmp, out);
}